// Round 1
// baseline (2131.790 us; speedup 1.0000x reference)
//
#include <hip/hip_runtime.h>
#include <hip/hip_bf16.h>

typedef short short8 __attribute__((ext_vector_type(8)));
typedef float f32x4 __attribute__((ext_vector_type(4)));
typedef float float4g __attribute__((ext_vector_type(4)));
typedef unsigned short ushort;

#define LOG2E 1.44269504088896f

__device__ __forceinline__ float dpp_xor8(float v) {
  // row_ror:8 within 16-lane row == xor-8 swap of lane halves (full-rate VALU)
  int i = __builtin_bit_cast(int, v);
  i = __builtin_amdgcn_mov_dpp(i, 0x128, 0xF, 0xF, true);
  return __builtin_bit_cast(float, i);
}
__device__ __forceinline__ ushort f2bf(float f) {
  __hip_bfloat16 h = __float2bfloat16(f);
  return __builtin_bit_cast(ushort, h);
}
__device__ __forceinline__ float sigmoid_pre(float m) {
  // given m = -log2e*x returns 1/(1+2^m) = sigmoid(x)
  return __builtin_amdgcn_rcpf(1.0f + __builtin_amdgcn_exp2f(m));
}

// ---------------- prep: swizzle weights to bf16 MFMA B-fragment blocks ----------------
// wfrag layout: [w(8)][l(4)][nt(2)][kc(4)][lane(64)][8 bf16]; K = [input(64)|hidden(64)]
// gate slice per wave w: hcols [w*8,w*8+8), tiles: nt0=[i|f], nt1=[g|o]
__global__ void prep_kernel(const float* __restrict__ Wih0, const float* __restrict__ Wihr,
                            const float* __restrict__ Whh, const float* __restrict__ bih,
                            const float* __restrict__ bhh, const float* __restrict__ Wo,
                            ushort* __restrict__ wfrag, ushort* __restrict__ wofrag,
                            float* __restrict__ bsum) {
  int id = blockIdx.x * 256 + threadIdx.x;
  if (id < 131072) {
    int j = id & 7, lane = (id >> 3) & 63, kc = (id >> 9) & 3, nt = (id >> 11) & 1,
        l = (id >> 12) & 3, w = id >> 14;
    int c16 = lane & 15, qq = lane >> 4;
    int gate = nt * 2 + (c16 >= 8 ? 1 : 0);
    int n = gate * 64 + w * 8 + (c16 & 7);
    int k = kc * 32 + qq * 8 + j;
    float v;
    if (k < 64) {
      if (l == 0) v = (k < 3) ? Wih0[n * 3 + k] : 0.0f;
      else        v = Wihr[((l - 1) * 256 + n) * 64 + k];
    } else {
      v = Whh[(l * 256 + n) * 64 + (k - 64)];
    }
    wfrag[id] = f2bf(v);
  } else if (id < 132096) {
    int id2 = id - 131072;
    int j = id2 & 7, lane = (id2 >> 3) & 63, kc = id2 >> 9;
    int c16 = lane & 15, qq = lane >> 4;
    int k = kc * 32 + qq * 8 + j;
    float v = (c16 < 3) ? Wo[c16 * 64 + k] : 0.0f;
    wofrag[id2] = f2bf(v);
  } else if (id < 133120) {
    int n2 = id - 132096;
    bsum[n2] = bih[n2] + bhh[n2];
  }
}

// ---------------- main persistent LSTM kernel ----------------
// 512 thr = 8 waves; wave w: weight-stationary slice = all-4-layers x 32 gates (hcols w*8..w*8+8
// as i,f,g,o). Block owns 64 batch rows; h via LDS bf16; c fp32 in regs (lane-half split by mtile).
__global__ __launch_bounds__(512, 2)
void lstm_kernel(const float* __restrict__ conds, const float* __restrict__ W1,
                 const float* __restrict__ b1, const float* __restrict__ W2,
                 const float* __restrict__ b2, const float* __restrict__ bo,
                 const int* __restrict__ seqp,
                 const ushort* __restrict__ wfrag, const ushort* __restrict__ wofrag,
                 const float* __restrict__ bsum, float* __restrict__ out) {
  __shared__ __align__(16) ushort h_lds[4][64][72];   // 36864 B, stride 144B: A-frag b128 conflict-free
  __shared__ __align__(16) ushort x_lds[64][40];      // 5120 B, x-input (cols 0..2), rest zero
  __shared__ __align__(16) float fc_scratch[64][64];  // 16384 B: h1 then c0
  __shared__ __align__(16) ushort wo_lds[1024];       // 2048 B   -> total 60416 B

  const int tid = threadIdx.x;
  const int w = tid >> 6;
  const int lane = tid & 63;
  const int c16 = lane & 15;
  const int q = lane >> 4;
  const bool lo8 = (c16 < 8);
  const int whc = w * 8 + (c16 & 7);
  const int T = *seqp;
  const int row0 = blockIdx.x * 64;

  for (int i = tid; i < 1024; i += 512) wo_lds[i] = wofrag[i];
  if (tid < 64) {
    x_lds[tid][0] = f2bf(0.5f);
    x_lds[tid][1] = f2bf(0.5f);
    for (int c = 2; c < 40; ++c) x_lds[tid][c] = 0;
  }

  // FC prologue A: h1 = relu(conds @ W1^T + b1)
  {
    const int r = tid >> 3;
    const int i8 = (tid & 7) * 8;
    float xr[8];
#pragma unroll
    for (int k = 0; k < 8; ++k) xr[k] = conds[(long)(row0 + r) * 8 + k];
#pragma unroll
    for (int jj = 0; jj < 8; ++jj) {
      float s = b1[i8 + jj];
#pragma unroll
      for (int k = 0; k < 8; ++k) s = fmaf(xr[k], W1[(i8 + jj) * 8 + k], s);
      fc_scratch[r][i8 + jj] = fmaxf(s, 0.0f);
    }
  }
  __syncthreads();
  // FC prologue B: ce = h1 @ W2^T + b2 (kept in regs)
  float ce[16];
  {
    const int r = tid >> 3;
    const int j16 = (tid & 7) * 16;
#pragma unroll
    for (int jj = 0; jj < 16; ++jj) {
      int jcol = j16 + jj;
      float s = b2[jcol];
      for (int k = 0; k < 64; k += 4) {
        float4g hv = *(const float4g*)&fc_scratch[r][k];
        float4g wv = *(const float4g*)&W2[jcol * 64 + k];
        s = fmaf(hv.x, wv.x, s); s = fmaf(hv.y, wv.y, s);
        s = fmaf(hv.z, wv.z, s); s = fmaf(hv.w, wv.w, s);
      }
      ce[jj] = s;
    }
  }
  __syncthreads();
  // scatter: ce[0:64] -> h0 (all 4 layers, bf16); ce[64:128] -> c0 scratch (fp32)
  {
    const int r = tid >> 3;
    const int j16 = (tid & 7) * 16;
#pragma unroll
    for (int jj = 0; jj < 16; ++jj) {
      int jcol = j16 + jj;
      if (jcol < 64) {
        ushort hb = f2bf(ce[jj]);
        h_lds[0][r][jcol] = hb; h_lds[1][r][jcol] = hb;
        h_lds[2][r][jcol] = hb; h_lds[3][r][jcol] = hb;
      } else {
        fc_scratch[r][jcol - 64] = ce[jj];
      }
    }
  }
  __syncthreads();

  // weight fragments -> registers (128 VGPRs)
  short8 wreg[4][2][4];
  {
    const ushort* base = wfrag + w * 16384;
#pragma unroll
    for (int l = 0; l < 4; ++l)
#pragma unroll
      for (int nt = 0; nt < 2; ++nt)
#pragma unroll
        for (int kc = 0; kc < 4; ++kc)
          wreg[l][nt][kc] = *(const short8*)(base + (((l * 2 + nt) * 4 + kc) * 64 + lane) * 8);
  }
  // per-lane activation constants & pre-scaled biases
  const float k1 = lo8 ? (2.0f * LOG2E) : (-LOG2E);
  const float a1c = lo8 ? -2.0f : 1.0f;
  const float c1c = lo8 ? 1.0f : 0.0f;
  float bt0[4], bt1[4];
  {
    int nrow0 = (c16 >= 8 ? 1 : 0) * 64 + whc;  // i|f
    int nrow1 = (c16 >= 8 ? 3 : 2) * 64 + whc;  // g|o
#pragma unroll
    for (int l = 0; l < 4; ++l) {
      bt0[l] = -LOG2E * bsum[l * 256 + nrow0];
      bt1[l] = k1 * bsum[l * 256 + nrow1];
    }
  }
  const float boc = (c16 < 3) ? bo[c16] : 0.0f;

  // c0 init: mt 0,1 live in lanes c16<8; mt 2,3 in lanes c16>=8
  float creg[4][2][4];
  {
    const int mtbase = lo8 ? 0 : 2;
#pragma unroll
    for (int p = 0; p < 2; ++p)
#pragma unroll
      for (int r = 0; r < 4; ++r) {
        float c0v = fc_scratch[(mtbase + p) * 16 + q * 4 + r][whc];
#pragma unroll
        for (int l = 0; l < 4; ++l) creg[l][p][r] = c0v;
      }
  }

  f32x4 accA[4], accB[4];
  for (int t = 0; t < T; ++t) {
#pragma unroll
    for (int l = 0; l < 4; ++l) {
      __syncthreads();  // prev writes (act l-1 / pred x) visible
      // ---- MFMA phase: gates for all 4 mtiles, this wave's 32 gate-cols ----
#pragma unroll
      for (int mt = 0; mt < 4; ++mt) {
        const int arow = mt * 16 + c16;
        short8 a0, a1v, a2, a3;
        if (l == 0) {
          a0 = *(const short8*)&x_lds[arow][q * 8];
        } else {
          a0 = *(const short8*)&h_lds[l - 1][arow][q * 8];
          a1v = *(const short8*)&h_lds[l - 1][arow][32 + q * 8];
        }
        a2 = *(const short8*)&h_lds[l][arow][q * 8];
        a3 = *(const short8*)&h_lds[l][arow][32 + q * 8];
        f32x4 A0 = {0.f, 0.f, 0.f, 0.f}, A1 = {0.f, 0.f, 0.f, 0.f};
        A0 = __builtin_amdgcn_mfma_f32_16x16x32_bf16(a0, wreg[l][0][0], A0, 0, 0, 0);
        A1 = __builtin_amdgcn_mfma_f32_16x16x32_bf16(a0, wreg[l][1][0], A1, 0, 0, 0);
        if (l != 0) {
          A0 = __builtin_amdgcn_mfma_f32_16x16x32_bf16(a1v, wreg[l][0][1], A0, 0, 0, 0);
          A1 = __builtin_amdgcn_mfma_f32_16x16x32_bf16(a1v, wreg[l][1][1], A1, 0, 0, 0);
        }
        A0 = __builtin_amdgcn_mfma_f32_16x16x32_bf16(a2, wreg[l][0][2], A0, 0, 0, 0);
        A1 = __builtin_amdgcn_mfma_f32_16x16x32_bf16(a2, wreg[l][1][2], A1, 0, 0, 0);
        A0 = __builtin_amdgcn_mfma_f32_16x16x32_bf16(a3, wreg[l][0][3], A0, 0, 0, 0);
        A1 = __builtin_amdgcn_mfma_f32_16x16x32_bf16(a3, wreg[l][1][3], A1, 0, 0, 0);
        accA[mt] = A0; accB[mt] = A1;
      }
      __syncthreads();  // all reads of old h_lds[l] done -> safe to write new h_l
      // ---- activation phase (lane-split: c16<8 = i|g side, c16>=8 = f|o side) ----
#pragma unroll
      for (int mt = 0; mt < 4; ++mt) {
        float hv4[4];
#pragma unroll
        for (int r = 0; r < 4; ++r) {
          float gif = accA[mt][r], ggo = accB[mt][r];
          float s0 = sigmoid_pre(fmaf(gif, -LOG2E, bt0[l]));  // sig(i)|sig(f)
          float r1 = sigmoid_pre(fmaf(ggo, k1, bt1[l]));
          float u = fmaf(r1, a1c, c1c);                       // tanh(g)|sig(o)
          float p = s0 * u;                                   // lanes<8: si*tg
          float sf = dpp_xor8(s0);                            // lanes<8 get sig(f)
          float cold = (mt < 2) ? creg[l][mt][r] : dpp_xor8(creg[l][mt - 2][r]);
          float cn = fmaf(sf, cold, p);                       // valid lanes<8
          if (mt < 2) {
            creg[l][mt][r] = lo8 ? cn : creg[l][mt][r];
          } else {
            float cs = dpp_xor8(cn);
            creg[l][mt - 2][r] = lo8 ? creg[l][mt - 2][r] : cs;
          }
          float tc = fmaf(sigmoid_pre(cn * (2.0f * LOG2E)), -2.0f, 1.0f);  // tanh(cn)
          float tcs = dpp_xor8(tc);                           // -> lanes>=8
          hv4[r] = u * tcs;                                   // lanes>=8: so*tanh(c)
        }
        if (!lo8) {
#pragma unroll
          for (int r = 0; r < 4; ++r)
            h_lds[l][mt * 16 + q * 4 + r][whc] = f2bf(hv4[r]);
        }
      }
    }
    __syncthreads();  // h_lds[3] complete
    // ---- pred phase: waves 0..3, one mtile each ----
    if (w < 4) {
      const int mt = w;
      const int arow = mt * 16 + c16;
      short8 a0 = *(const short8*)&h_lds[3][arow][q * 8];
      short8 a1v = *(const short8*)&h_lds[3][arow][32 + q * 8];
      short8 wo0 = *(const short8*)&wo_lds[lane * 8];
      short8 wo1 = *(const short8*)&wo_lds[(64 + lane) * 8];
      f32x4 P = {0.f, 0.f, 0.f, 0.f};
      P = __builtin_amdgcn_mfma_f32_16x16x32_bf16(a0, wo0, P, 0, 0, 0);
      P = __builtin_amdgcn_mfma_f32_16x16x32_bf16(a1v, wo1, P, 0, 0, 0);
      if (c16 < 3) {
#pragma unroll
        for (int r = 0; r < 4; ++r) {
          float pv = P[r] + boc;
          int rloc = mt * 16 + q * 4 + r;
          out[(long)(row0 + rloc) * (3 * T) + (long)t * 3 + c16] = pv;
          x_lds[rloc][c16] = f2bf(pv);
        }
      }
    }
  }
}

extern "C" void kernel_launch(void* const* d_in, const int* in_sizes, int n_in,
                              void* d_out, int out_size, void* d_ws, size_t ws_size,
                              hipStream_t stream) {
  const float* conds = (const float*)d_in[0];
  const float* W1    = (const float*)d_in[1];
  const float* b1    = (const float*)d_in[2];
  const float* W2    = (const float*)d_in[3];
  const float* b2    = (const float*)d_in[4];
  const float* Wih0  = (const float*)d_in[5];
  const float* Wihr  = (const float*)d_in[6];
  const float* Whh   = (const float*)d_in[7];
  const float* bih   = (const float*)d_in[8];
  const float* bhh   = (const float*)d_in[9];
  const float* Wo    = (const float*)d_in[10];
  const float* bo    = (const float*)d_in[11];
  const int*   seqp  = (const int*)d_in[12];

  const int B = in_sizes[0] / 8;  // 65536

  ushort* wfrag = (ushort*)d_ws;            // 131072 shorts
  ushort* wofrag = wfrag + 131072;          // 1024 shorts
  float* bsum = (float*)(wofrag + 1024);    // 1024 floats

  prep_kernel<<<520, 256, 0, stream>>>(Wih0, Wihr, Whh, bih, bhh, Wo, wfrag, wofrag, bsum);
  lstm_kernel<<<B / 64, 512, 0, stream>>>(conds, W1, b1, W2, b2, bo, seqp,
                                          wfrag, wofrag, bsum, (float*)d_out);
}

// Round 2
// 1598.649 us; speedup vs baseline: 1.3335x; 1.3335x over previous
//
#include <hip/hip_runtime.h>
#include <hip/hip_bf16.h>

typedef short short8 __attribute__((ext_vector_type(8)));
typedef float f32x4 __attribute__((ext_vector_type(4)));
typedef float float4g __attribute__((ext_vector_type(4)));
typedef unsigned short ushort;

#define LOG2E 1.44269504088896f

__device__ __forceinline__ ushort f2bf(float f) {
  __hip_bfloat16 h = __float2bfloat16(f);
  return __builtin_bit_cast(ushort, h);
}
__device__ __forceinline__ float sigmoid_pre(float m) {
  // m = -log2e*x  ->  1/(1+2^m) = sigmoid(x)
  return __builtin_amdgcn_rcpf(1.0f + __builtin_amdgcn_exp2f(m));
}
// merge: enabled banks (BM) get row_ror:8 of src, others keep old.
// BM=0xC -> lanes 8..15 of each 16-row updated; BM=0x3 -> lanes 0..7 updated.
template <int BM>
__device__ __forceinline__ float pkmerge(float oldv, float srcv) {
  int o = __builtin_bit_cast(int, oldv);
  int s = __builtin_bit_cast(int, srcv);
  int r = __builtin_amdgcn_update_dpp(o, s, 0x128 /*row_ror:8*/, 0xF, BM, false);
  return __builtin_bit_cast(float, r);
}

// ---------------- prep: swizzle weights to bf16 MFMA B-fragment blocks ----------------
// wfrag layout: [w(8)][l(4)][nt(2)][kc(4)][lane(64)][8 bf16]; K = [input(64)|hidden(64)]
// nt0 = [i|f], nt1 = [g|o]; wave w covers hcols [w*8, w*8+8)
__global__ void prep_kernel(const float* __restrict__ Wih0, const float* __restrict__ Wihr,
                            const float* __restrict__ Whh, const float* __restrict__ bih,
                            const float* __restrict__ bhh, const float* __restrict__ Wo,
                            ushort* __restrict__ wfrag, ushort* __restrict__ wofrag,
                            float* __restrict__ bsum) {
  int id = blockIdx.x * 256 + threadIdx.x;
  if (id < 131072) {
    int j = id & 7, lane = (id >> 3) & 63, kc = (id >> 9) & 3, nt = (id >> 11) & 1,
        l = (id >> 12) & 3, w = id >> 14;
    int c16 = lane & 15, qq = lane >> 4;
    int gate = nt * 2 + (c16 >= 8 ? 1 : 0);
    int n = gate * 64 + w * 8 + (c16 & 7);
    int k = kc * 32 + qq * 8 + j;
    float v;
    if (k < 64) {
      if (l == 0) v = (k < 3) ? Wih0[n * 3 + k] : 0.0f;
      else        v = Wihr[((l - 1) * 256 + n) * 64 + k];
    } else {
      v = Whh[(l * 256 + n) * 64 + (k - 64)];
    }
    wfrag[id] = f2bf(v);
  } else if (id < 132096) {
    int id2 = id - 131072;
    int j = id2 & 7, lane = (id2 >> 3) & 63, kc = id2 >> 9;
    int c16 = lane & 15, qq = lane >> 4;
    int k = kc * 32 + qq * 8 + j;
    float v = (c16 < 3) ? Wo[c16 * 64 + k] : 0.0f;
    wofrag[id2] = f2bf(v);
  } else if (id < 133120) {
    int n2 = id - 132096;
    bsum[n2] = bih[n2] + bhh[n2];
  }
}

// ---------------- main persistent LSTM kernel ----------------
// 8 waves; wave w: weight-stationary, all 4 layers x 32 gate-cols (hcols w*8..+8 as i,f,g,o).
// Block owns 64 batch rows. h: 5 rotating LDS bf16 buffers (no WAR barrier -> 5 barriers/t).
// Activation packed: lanes (c16<8) carry mt-pair member A, lanes (c16>=8) member B via
// single-instr update_dpp merges -> full-lane transcendentals (10 per 64 elems = floor).
__global__ __launch_bounds__(512, 2)
void lstm_kernel(const float* __restrict__ conds, const float* __restrict__ W1,
                 const float* __restrict__ b1, const float* __restrict__ W2,
                 const float* __restrict__ b2, const float* __restrict__ bo,
                 const int* __restrict__ seqp,
                 const ushort* __restrict__ wfrag, const ushort* __restrict__ wofrag,
                 const float* __restrict__ bsum, float* __restrict__ out) {
  // 5 h-buffers (64x72 ushort = 9216 B each) + x (64x32 ushort = 4096 B) = 50176 B
  __shared__ __align__(16) char smem[5 * 9216 + 4096];
  ushort* xb = (ushort*)(smem + 5 * 9216);
  float* fc = (float*)smem;  // prologue alias over h-buffers 0..1 (16384 <= 18432)

  const int tid = threadIdx.x;
  const int w = tid >> 6;
  const int lane = tid & 63;
  const int c16 = lane & 15;
  const int q = lane >> 4;
  const int hi16 = (c16 < 8) ? 0 : 16;  // packed-half row offset
  const int colw = w * 8 + (c16 & 7);   // this lane's h-column
  const int T = *seqp;
  const int row0 = blockIdx.x * 64;

  // ---- prologue A: h1 = relu(conds @ W1^T + b1) -> fc (fp32, aliases hbuf0..1) ----
  {
    const int r = tid >> 3;
    const int i8 = (tid & 7) * 8;
    float xr[8];
#pragma unroll
    for (int k = 0; k < 8; ++k) xr[k] = conds[(long)(row0 + r) * 8 + k];
#pragma unroll
    for (int jj = 0; jj < 8; ++jj) {
      float s = b1[i8 + jj];
#pragma unroll
      for (int k = 0; k < 8; ++k) s = fmaf(xr[k], W1[(i8 + jj) * 8 + k], s);
      fc[r * 64 + i8 + jj] = fmaxf(s, 0.0f);
    }
  }
  __syncthreads();

  // ---- prologue B1: per-lane fp32 c0 = (h1 @ W2^T + b2)[64+colw] at its packed rows ----
  float cinit[2][4];
  {
    const float b2v = b2[64 + colw];
#pragma unroll
    for (int pr = 0; pr < 2; ++pr)
#pragma unroll
      for (int r = 0; r < 4; ++r) cinit[pr][r] = b2v;
    const float* w2r = W2 + (64 + colw) * 64;
    const int rbase = hi16 + q * 4;
#pragma unroll 2
    for (int k4 = 0; k4 < 16; ++k4) {
      float4g wv = *(const float4g*)(w2r + k4 * 4);
#pragma unroll
      for (int pr = 0; pr < 2; ++pr)
#pragma unroll
        for (int r = 0; r < 4; ++r) {
          float4g hv = *(const float4g*)(fc + (pr * 32 + rbase + r) * 64 + k4 * 4);
          cinit[pr][r] = fmaf(hv.x, wv.x, cinit[pr][r]);
          cinit[pr][r] = fmaf(hv.y, wv.y, cinit[pr][r]);
          cinit[pr][r] = fmaf(hv.z, wv.z, cinit[pr][r]);
          cinit[pr][r] = fmaf(hv.w, wv.w, cinit[pr][r]);
        }
    }
  }
  // ---- prologue B2: h0 cols (thread-per-row) ----
  float ce0[8];
  {
    const int rb = tid >> 3;
    const int cb = (tid & 7) * 8;
#pragma unroll
    for (int jj = 0; jj < 8; ++jj) {
      float s = b2[cb + jj];
      for (int k = 0; k < 64; k += 4) {
        float4g hv = *(const float4g*)(fc + rb * 64 + k);
        float4g wv = *(const float4g*)(W2 + (cb + jj) * 64 + k);
        s = fmaf(hv.x, wv.x, s); s = fmaf(hv.y, wv.y, s);
        s = fmaf(hv.z, wv.z, s); s = fmaf(hv.w, wv.w, s);
      }
      ce0[jj] = s;
    }
  }
  __syncthreads();

  // ---- prologue C: scatter h0 into buffers 0..3 (overwrites fc alias), init x ----
  {
    const int rb = tid >> 3;
    const int cb = (tid & 7) * 8;
#pragma unroll
    for (int jj = 0; jj < 8; ++jj) {
      ushort hb = f2bf(ce0[jj]);
#pragma unroll
      for (int b = 0; b < 4; ++b)
        ((ushort*)(smem + b * 9216))[rb * 72 + cb + jj] = hb;
    }
  }
  if (tid < 64) {
    for (int c = 0; c < 32; ++c) xb[tid * 32 + c] = 0;
    xb[tid * 32 + 0] = f2bf(0.5f);
    xb[tid * 32 + 1] = f2bf(0.5f);
  }

  // ---- weight fragments -> registers (128 VGPR/AGPR) ----
  short8 wreg[4][2][4];
  {
    const ushort* base = wfrag + w * 16384;
#pragma unroll
    for (int l = 0; l < 4; ++l)
#pragma unroll
      for (int nt = 0; nt < 2; ++nt)
#pragma unroll
        for (int kc = 0; kc < 4; ++kc)
          wreg[l][nt][kc] = *(const short8*)(base + (((l * 2 + nt) * 4 + kc) * 64 + lane) * 8);
  }
  short8 wo0 = *(const short8*)(wofrag + lane * 8);
  short8 wo1 = *(const short8*)(wofrag + 512 + lane * 8);

  // pre-scaled gate biases (uniform across packed halves: depends only on colw)
  float bti[4], btf[4], btg[4], bto[4];
#pragma unroll
  for (int l = 0; l < 4; ++l) {
    bti[l] = -LOG2E * bsum[l * 256 + colw];
    btf[l] = -LOG2E * bsum[l * 256 + 64 + colw];
    btg[l] = -2.0f * LOG2E * bsum[l * 256 + 128 + colw];
    bto[l] = -LOG2E * bsum[l * 256 + 192 + colw];
  }
  const float boc = (c16 < 3) ? bo[c16] : 0.0f;

  // c-state fp32, packed layout (lane half <-> mt-pair member)
  float creg[4][2][4];
#pragma unroll
  for (int l = 0; l < 4; ++l)
#pragma unroll
    for (int pr = 0; pr < 2; ++pr)
#pragma unroll
      for (int r = 0; r < 4; ++r) creg[l][pr][r] = cinit[pr][r];

  int cur[4] = {0, 1, 2, 3};
  int spare = 4;
  __syncthreads();

  f32x4 accA[4], accB[4];
  for (int t = 0; t < T; ++t) {
#pragma unroll
    for (int l = 0; l < 4; ++l) {
      __syncthreads();  // new h_{l-1} (or x/pred) visible; old-h_l readers done
      const ushort* hc = (const ushort*)(smem + cur[l] * 9216);
      const ushort* hp = (l == 0) ? xb : (const ushort*)(smem + cur[l - 1] * 9216);
      // ---- MFMA phase ----
#pragma unroll
      for (int mt = 0; mt < 4; ++mt) {
        const int arow = mt * 16 + c16;
        short8 a0, a1v;
        if (l == 0) {
          a0 = *(const short8*)(hp + arow * 32 + q * 8);
        } else {
          a0 = *(const short8*)(hp + arow * 72 + q * 8);
          a1v = *(const short8*)(hp + arow * 72 + 32 + q * 8);
        }
        short8 a2 = *(const short8*)(hc + arow * 72 + q * 8);
        short8 a3 = *(const short8*)(hc + arow * 72 + 32 + q * 8);
        f32x4 A0 = {0.f, 0.f, 0.f, 0.f}, A1 = {0.f, 0.f, 0.f, 0.f};
        A0 = __builtin_amdgcn_mfma_f32_16x16x32_bf16(a0, wreg[l][0][0], A0, 0, 0, 0);
        A1 = __builtin_amdgcn_mfma_f32_16x16x32_bf16(a0, wreg[l][1][0], A1, 0, 0, 0);
        if (l != 0) {
          A0 = __builtin_amdgcn_mfma_f32_16x16x32_bf16(a1v, wreg[l][0][1], A0, 0, 0, 0);
          A1 = __builtin_amdgcn_mfma_f32_16x16x32_bf16(a1v, wreg[l][1][1], A1, 0, 0, 0);
        }
        A0 = __builtin_amdgcn_mfma_f32_16x16x32_bf16(a2, wreg[l][0][2], A0, 0, 0, 0);
        A1 = __builtin_amdgcn_mfma_f32_16x16x32_bf16(a2, wreg[l][1][2], A1, 0, 0, 0);
        A0 = __builtin_amdgcn_mfma_f32_16x16x32_bf16(a3, wreg[l][0][3], A0, 0, 0, 0);
        A1 = __builtin_amdgcn_mfma_f32_16x16x32_bf16(a3, wreg[l][1][3], A1, 0, 0, 0);
        accA[mt] = A0; accB[mt] = A1;
      }
      // ---- packed activation phase: write new h_l into spare buffer ----
      {
        ushort* wbuf = (ushort*)(smem + spare * 9216);
#pragma unroll
        for (int pr = 0; pr < 2; ++pr) {
          const int mtA = pr * 2, mtB = pr * 2 + 1;
          ushort* wb = wbuf + (pr * 32 + hi16 + q * 4) * 72 + colw;
#pragma unroll
          for (int r = 0; r < 4; ++r) {
            float ipk = pkmerge<0xC>(accA[mtA][r], accA[mtB][r]);
            float fpk = pkmerge<0x3>(accA[mtB][r], accA[mtA][r]);
            float gpk = pkmerge<0xC>(accB[mtA][r], accB[mtB][r]);
            float opk = pkmerge<0x3>(accB[mtB][r], accB[mtA][r]);
            float si = sigmoid_pre(fmaf(ipk, -LOG2E, bti[l]));
            float sf = sigmoid_pre(fmaf(fpk, -LOG2E, btf[l]));
            float so = sigmoid_pre(fmaf(opk, -LOG2E, bto[l]));
            float tg = fmaf(sigmoid_pre(fmaf(gpk, -2.0f * LOG2E, btg[l])), 2.0f, -1.0f);
            float cn = fmaf(sf, creg[l][pr][r], si * tg);
            creg[l][pr][r] = cn;
            float tc = fmaf(sigmoid_pre(cn * (2.0f * LOG2E)), -2.0f, 1.0f);
            wb[r * 72] = f2bf(so * tc);
          }
        }
      }
      const int sp = spare; spare = cur[l]; cur[l] = sp;  // rotate
    }
    __syncthreads();  // h_3 (new) visible
    // ---- pred phase: waves 0..3, one mtile each ----
    if (w < 4) {
      const ushort* h3 = (const ushort*)(smem + cur[3] * 9216);
      const int arow = w * 16 + c16;
      short8 a0 = *(const short8*)(h3 + arow * 72 + q * 8);
      short8 a1v = *(const short8*)(h3 + arow * 72 + 32 + q * 8);
      f32x4 P = {0.f, 0.f, 0.f, 0.f};
      P = __builtin_amdgcn_mfma_f32_16x16x32_bf16(a0, wo0, P, 0, 0, 0);
      P = __builtin_amdgcn_mfma_f32_16x16x32_bf16(a1v, wo1, P, 0, 0, 0);
      if (c16 < 3) {
#pragma unroll
        for (int r = 0; r < 4; ++r) {
          float pv = P[r] + boc;
          int rloc = w * 16 + q * 4 + r;
          out[(long)(row0 + rloc) * (3 * T) + (long)t * 3 + c16] = pv;
          xb[rloc * 32 + c16] = f2bf(pv);
        }
      }
    }
  }
}

extern "C" void kernel_launch(void* const* d_in, const int* in_sizes, int n_in,
                              void* d_out, int out_size, void* d_ws, size_t ws_size,
                              hipStream_t stream) {
  const float* conds = (const float*)d_in[0];
  const float* W1    = (const float*)d_in[1];
  const float* b1    = (const float*)d_in[2];
  const float* W2    = (const float*)d_in[3];
  const float* b2    = (const float*)d_in[4];
  const float* Wih0  = (const float*)d_in[5];
  const float* Wihr  = (const float*)d_in[6];
  const float* Whh   = (const float*)d_in[7];
  const float* bih   = (const float*)d_in[8];
  const float* bhh   = (const float*)d_in[9];
  const float* Wo    = (const float*)d_in[10];
  const float* bo    = (const float*)d_in[11];
  const int*   seqp  = (const int*)d_in[12];

  const int B = in_sizes[0] / 8;  // 65536

  ushort* wfrag = (ushort*)d_ws;            // 131072 shorts
  ushort* wofrag = wfrag + 131072;          // 1024 shorts
  float* bsum = (float*)(wofrag + 1024);    // 1024 floats

  prep_kernel<<<520, 256, 0, stream>>>(Wih0, Wihr, Whh, bih, bhh, Wo, wfrag, wofrag, bsum);
  lstm_kernel<<<B / 64, 512, 0, stream>>>(conds, W1, b1, W2, b2, bo, seqp,
                                          wfrag, wofrag, bsum, (float*)d_out);
}